// Round 1
// baseline (109.757 us; speedup 1.0000x reference)
//
#include <hip/hip_runtime.h>
#include <hip/hip_bf16.h>
#include <math.h>

#define N_NODES 8192
#define F_IN    512
#define C_OUT   128
#define EDGE_CAP 512
#define NEG_SLOPE 0.2f

// ---------------------------------------------------------------------------
// Kernel 1: ft = X @ W  (8192x512 @ 512x128), fused with
//   a_src[i] = ft[i]·att_src, a_dst[i] = ft[i]·att_dst, and per-block
//   column-sum partials (for S = sum_i ft[i]).
// 256 threads/block, each block does 32 rows x 128 cols, thread = 4x4 tile.
// ---------------------------------------------------------------------------
__global__ void __launch_bounds__(256) gemm_ft_kernel(
    const float* __restrict__ X, const float* __restrict__ W,
    const float* __restrict__ att_src, const float* __restrict__ att_dst,
    float* __restrict__ ft, float* __restrict__ asrc, float* __restrict__ adst,
    float* __restrict__ Spart)
{
  __shared__ float sf[32][32];    // featT [k][row]
  __shared__ float sk[32][128];   // W tile [k][col]
  const int tid  = threadIdx.x;
  const int row0 = blockIdx.x * 32;
  const int g    = tid >> 5;        // 0..7
  const int r0   = g * 4;           // row offset in tile
  const int c0   = (tid & 31) * 4;  // col offset
  const int fr   = tid & 31;        // staging: feature row
  const int fk   = g * 4;           // staging: k group

  float acc[4][4] = {};

  for (int kt = 0; kt < F_IN; kt += 32) {
    // stage features (transposed) : 32 rows x 32 k
    float4 fv = *(const float4*)(X + (size_t)(row0 + fr) * F_IN + kt + fk);
    sf[fk + 0][fr] = fv.x; sf[fk + 1][fr] = fv.y;
    sf[fk + 2][fr] = fv.z; sf[fk + 3][fr] = fv.w;
    // stage W tile : 32 k x 128 c
    #pragma unroll
    for (int i = 0; i < 4; ++i) {
      int idx = i * 256 + tid;
      int kk  = idx >> 5;
      int cc  = (idx & 31) * 4;
      *(float4*)&sk[kk][cc] = *(const float4*)(W + (size_t)(kt + kk) * C_OUT + cc);
    }
    __syncthreads();
    #pragma unroll
    for (int k = 0; k < 32; ++k) {
      float4 a = *(const float4*)&sf[k][r0];
      float4 b = *(const float4*)&sk[k][c0];
      float av[4] = {a.x, a.y, a.z, a.w};
      float bv[4] = {b.x, b.y, b.z, b.w};
      #pragma unroll
      for (int i = 0; i < 4; ++i)
        #pragma unroll
        for (int j = 0; j < 4; ++j)
          acc[i][j] += av[i] * bv[j];
    }
    __syncthreads();
  }

  // write ft
  #pragma unroll
  for (int i = 0; i < 4; ++i) {
    float4 o = make_float4(acc[i][0], acc[i][1], acc[i][2], acc[i][3]);
    *(float4*)(ft + (size_t)(row0 + r0 + i) * C_OUT + c0) = o;
  }

  // a_src / a_dst : reduce over the 32 threads sharing rows (width-32 butterfly)
  float4 as = *(const float4*)(att_src + c0);
  float4 ad = *(const float4*)(att_dst + c0);
  #pragma unroll
  for (int i = 0; i < 4; ++i) {
    float ps = acc[i][0]*as.x + acc[i][1]*as.y + acc[i][2]*as.z + acc[i][3]*as.w;
    float pd = acc[i][0]*ad.x + acc[i][1]*ad.y + acc[i][2]*ad.z + acc[i][3]*ad.w;
    #pragma unroll
    for (int off = 16; off > 0; off >>= 1) {
      ps += __shfl_xor(ps, off, 32);
      pd += __shfl_xor(pd, off, 32);
    }
    if ((tid & 31) == 0) {
      asrc[row0 + r0 + i] = ps;
      adst[row0 + r0 + i] = pd;
    }
  }

  // column-sum partials (reuse sf as [8][128] scratch; safe: all sf reads done)
  float* scp = (float*)sf;
  float cp0 = acc[0][0] + acc[1][0] + acc[2][0] + acc[3][0];
  float cp1 = acc[0][1] + acc[1][1] + acc[2][1] + acc[3][1];
  float cp2 = acc[0][2] + acc[1][2] + acc[2][2] + acc[3][2];
  float cp3 = acc[0][3] + acc[1][3] + acc[2][3] + acc[3][3];
  *(float4*)&scp[g * 128 + c0] = make_float4(cp0, cp1, cp2, cp3);
  __syncthreads();
  if (tid < 128) {
    float s = 0.f;
    #pragma unroll
    for (int q = 0; q < 8; ++q) s += scp[q * 128 + tid];
    Spart[(size_t)blockIdx.x * 128 + tid] = s;
  }
}

// ---------------------------------------------------------------------------
// Kernel 2: S[c] = sum over 256 block partials (deterministic)
// ---------------------------------------------------------------------------
__global__ void colsum2_kernel(const float* __restrict__ Spart,
                               float* __restrict__ S)
{
  int c = threadIdx.x;
  float s = 0.f;
  for (int b = 0; b < 256; ++b) s += Spart[(size_t)b * 128 + c];
  S[c] = s;
}

// ---------------------------------------------------------------------------
// Kernel 3: one block per row i.
//  phase 1: scan adjacency row (coalesced float4), build deterministic edge
//           list via LDS prefix scan.
//  phase 2: row max / sum-exp over edges + implicit zeros -> softmax params.
//  phase 3: out[i] = base*S + sum_e (w_e - base) * ft[j_e], then ELU.
// ---------------------------------------------------------------------------
__global__ void __launch_bounds__(256) gat_row_kernel(
    const float* __restrict__ adj, const float* __restrict__ ft,
    const float* __restrict__ asrc, const float* __restrict__ adst,
    const float* __restrict__ S, float* __restrict__ out)
{
  __shared__ int   elist[EDGE_CAP];
  __shared__ float evals[EDGE_CAP];
  __shared__ int   scan[256];
  __shared__ float red[256];

  const int i = blockIdx.x;
  const int t = threadIdx.x;
  const float4* arow = (const float4*)(adj + (size_t)i * N_NODES);

  // ---- phase 1: nonzero bitmask (coalesced), prefix scan, edge list
  unsigned msk = 0u;
  #pragma unroll
  for (int k = 0; k < 8; ++k) {
    float4 v = arow[k * 256 + t];
    unsigned b = 0u;
    if (v.x != 0.f) b |= 1u;
    if (v.y != 0.f) b |= 2u;
    if (v.z != 0.f) b |= 4u;
    if (v.w != 0.f) b |= 8u;
    msk |= b << (k * 4);
  }
  int cnt = __popc(msk);
  scan[t] = cnt;
  __syncthreads();
  for (int off = 1; off < 256; off <<= 1) {
    int add = (t >= off) ? scan[t - off] : 0;
    __syncthreads();
    scan[t] += add;
    __syncthreads();
  }
  const int deg = scan[255];
  int wo = scan[t] - cnt;          // exclusive offset
  unsigned mm = msk;
  while (mm) {
    int b = __ffs(mm) - 1;
    mm &= mm - 1;
    if (wo < EDGE_CAP)
      elist[wo] = (((b >> 2) * 256 + t) << 2) + (b & 3);
    ++wo;
  }
  __syncthreads();

  const int degc = deg < EDGE_CAP ? deg : EDGE_CAP;
  const float ai = asrc[i];

  // ---- phase 2a: leaky-relu scores, max (implicit zeros -> init 0)
  float lmax = 0.f;
  for (int e = t; e < degc; e += 256) {
    float s = ai + adst[elist[e]];
    float l = s < 0.f ? NEG_SLOPE * s : s;
    evals[e] = l;
    lmax = fmaxf(lmax, l);
  }
  red[t] = lmax;
  __syncthreads();
  #pragma unroll
  for (int off = 128; off > 0; off >>= 1) {
    if (t < off) red[t] = fmaxf(red[t], red[t + off]);
    __syncthreads();
  }
  const float mI = red[0];
  __syncthreads();

  // ---- phase 2b: sum of exp (edges) + implicit zeros term
  float lsum = 0.f;
  for (int e = t; e < degc; e += 256) lsum += expf(evals[e] - mI);
  red[t] = lsum;
  __syncthreads();
  #pragma unroll
  for (int off = 128; off > 0; off >>= 1) {
    if (t < off) red[t] += red[t + off];
    __syncthreads();
  }
  const float enm   = expf(-mI);
  const float denom = red[0] + (float)(N_NODES - deg) * enm;
  const float base  = enm / denom;
  __syncthreads();

  // ---- phase 2c: per-edge weight minus baseline
  for (int e = t; e < degc; e += 256)
    evals[e] = expf(evals[e] - mI) / denom - base;
  __syncthreads();

  // ---- phase 3: gather ft rows; 2 edge-parity groups x 128 channels
  const int c = t & 127;
  const int p = t >> 7;
  float a0 = 0.f;
  for (int e = p; e < degc; e += 2)
    a0 += evals[e] * ft[(size_t)elist[e] * C_OUT + c];
  red[t] = a0;
  __syncthreads();
  if (t < 128) {
    float o = base * S[c] + red[t] + red[t + 128];
    out[(size_t)i * C_OUT + c] = o > 0.f ? o : expm1f(o);
  }
}

// ---------------------------------------------------------------------------
extern "C" void kernel_launch(void* const* d_in, const int* in_sizes, int n_in,
                              void* d_out, int out_size, void* d_ws, size_t ws_size,
                              hipStream_t stream)
{
  const float* X       = (const float*)d_in[0];   // features 8192x512
  const float* adj     = (const float*)d_in[1];   // adjacency 8192x8192
  const float* W       = (const float*)d_in[2];   // kernel 512x128
  const float* att_src = (const float*)d_in[3];   // 128
  const float* att_dst = (const float*)d_in[4];   // 128
  float* out = (float*)d_out;

  float* ws    = (float*)d_ws;
  float* ft    = ws;                                   // 8192*128
  float* asrc  = ft + (size_t)N_NODES * C_OUT;         // 8192
  float* adst  = asrc + N_NODES;                       // 8192
  float* Spart = adst + N_NODES;                       // 256*128
  float* S     = Spart + 256 * 128;                    // 128

  gemm_ft_kernel<<<N_NODES / 32, 256, 0, stream>>>(X, W, att_src, att_dst,
                                                   ft, asrc, adst, Spart);
  colsum2_kernel<<<1, 128, 0, stream>>>(Spart, S);
  gat_row_kernel<<<N_NODES, 256, 0, stream>>>(adj, ft, asrc, adst, S, out);
}